// Round 6
// baseline (464.881 us; speedup 1.0000x reference)
//
#include <hip/hip_runtime.h>
#include <hip/hip_bf16.h>

// LSTM B=4096 T=512 IN=14 H=28 OUT=2, fp32 in/out.
// R6: register-resident recurrence, ZERO LDS/barriers in the per-step chain.
// Orientation: D = Wperm @ [h;x], M=112 gate rows (7 tiles), N=16 batches.
// Wperm tile mt, row q*4+r = gate r of unit u = q*7+mt.  Then lane (q,m)'s
// MFMA output acc[mt] = 4 gate preacts of unit q*7+mt, batch m -> combine
// fully in-register; new h[q*7+mt] is exactly this lane's next B-fragment
// slot k=q*8+mt (k-slots j=7 are zero columns in W_hh-A).  x enters as
// k-tile1 B-frag via 2 broadcast ds_reads (prefetched) + cvt_pk; cols >=14
// of W_ih-A are zero so garbage lanes are harmless.  Weights/bias pre-scaled
// by -log2(e) (g-gate by -2log2(e)) so exps are raw v_exp_f32 of acc.
// 256 single-wave blocks; each wave = one independent 16-batch chain.

#define T_STEPS 512
#define BATCH   4096
#define IN_F    14
#define HID     28
#define OUT_N   2
#define WB      16                 // batches per wave (MFMA N)
#define TC      64                 // timesteps per x chunk
#define NCHUNK  (T_STEPS / TC)     // 8
#define XP      900                // LDS floats per batch row (64*14=896 used)
#define QCH     (TC * IN_F / 4)    // 224 floats staged per lane-quarter

typedef __attribute__((ext_vector_type(8))) short  short8;
typedef __attribute__((ext_vector_type(4))) float  float4v;

#define L1 1.4426950408889634f     // log2(e)

__device__ __forceinline__ unsigned short f2bf(float f) {
    union { float f; unsigned int u; } v; v.f = f;
    unsigned int r = (v.u + 0x7FFFu + ((v.u >> 16) & 1u)) >> 16;  // RNE
    return (unsigned short)r;
}

__device__ __forceinline__ int pk2(float a, float b) {   // bf16(a) | bf16(b)<<16
    __hip_bfloat162 t = __float22bfloat162_rn(float2{a, b});
    union { __hip_bfloat162 h; int i; } u; u.h = t; return u.i;
}

union S8 { int i[4]; short8 s; };

__global__ __launch_bounds__(64, 1)
void lstm_reg(const float* __restrict__ x,
              const float* __restrict__ W_ih,
              const float* __restrict__ W_hh,
              const float* __restrict__ b_ih,
              const float* __restrict__ b_hh,
              const float* __restrict__ W_out,
              const float* __restrict__ b_out,
              float* __restrict__ out) {
    __shared__ __align__(16) float xrow[WB * XP];   // 57.6 KB fp32 x chunk

    const int l  = threadIdx.x;
    const int q  = l >> 4;           // 0..3
    const int m  = l & 15;           // batch column / A-row
    const int b0 = blockIdx.x * WB;

    // ---- A-fragments (Wperm, pre-scaled, bf16) + scaled bias ----
    // Tile mt, A-row i=m: gate r=m&3, unit u=(m>>2)*7+mt; A[i][k=q*8+j].
    short8  wa0[7], wa1[7];          // k-tile0 = h-cols, k-tile1 = x-cols
    float4v biasv[7];
    #pragma unroll
    for (int mt = 0; mt < 7; ++mt) {
        const int r    = m & 3;
        const int uu   = (m >> 2) * 7 + mt;
        const int orow = r * HID + uu;
        const float sc = (r == 2) ? (-2.0f * L1) : (-L1);
        S8 v0, v1;
        #pragma unroll
        for (int jj = 0; jj < 4; ++jj) {
            // h-cols: k=q*8+j -> unit q*7+j (j<7), j==7 -> zero column
            int j0 = 2 * jj, j1 = 2 * jj + 1;
            float wh0 = (j0 < 7) ? W_hh[orow * HID + (q * 7 + j0)] * sc : 0.0f;
            float wh1 = (j1 < 7) ? W_hh[orow * HID + (q * 7 + j1)] * sc : 0.0f;
            v0.i[jj] = pk2(wh0, wh1);
            // x-cols: f=q*8+j, zero for f>=14
            int f0 = q * 8 + j0, f1 = q * 8 + j1;
            float wx0 = (f0 < IN_F) ? W_ih[orow * IN_F + f0] * sc : 0.0f;
            float wx1 = (f1 < IN_F) ? W_ih[orow * IN_F + f1] * sc : 0.0f;
            v1.i[jj] = pk2(wx0, wx1);
        }
        wa0[mt] = v0.s; wa1[mt] = v1.s;
        // bias: D rows i=q*4+rr -> gate rr of unit q*7+mt (scaled)
        float4v bv;
        #pragma unroll
        for (int rr = 0; rr < 4; ++rr) {
            const int br = rr * HID + (q * 7 + mt);
            const float s2 = (rr == 2) ? (-2.0f * L1) : (-L1);
            bv[rr] = (b_ih[br] + b_hh[br]) * s2;
        }
        biasv[mt] = bv;
    }

    // ---- state ----
    short8 hfrag = {0, 0, 0, 0, 0, 0, 0, 0};   // h0 = 0
    float  cc[7] = {0, 0, 0, 0, 0, 0, 0};
    float  hn[7] = {0, 0, 0, 0, 0, 0, 0};

    const float* xsrc = x + (long)(b0 + m) * T_STEPS * IN_F + q * QCH;
    float*       xdst = &xrow[m * XP + q * QCH];
    const int    rbase = m * XP + (q & 1) * 8;   // broadcast read base

    for (int ch = 0; ch < NCHUNK; ++ch) {
        // ---- stage chunk: 56 b128 global->LDS copies per lane ----
        __syncthreads();                          // prior chunk's reads done
        const float* s = xsrc + ch * (TC * IN_F);
        #pragma unroll 4
        for (int i = 0; i < QCH / 4; ++i)
            *(float4*)(xdst + 4 * i) = *(const float4*)(s + 4 * i);
        __syncthreads();                          // chunk visible

        // prefetch x for tt=0
        float4 xa = *(const float4*)&xrow[rbase + 0];
        float4 xb = *(const float4*)&xrow[rbase + 4];

        for (int tt = 0; tt < TC; ++tt) {
            // ---- build x B-fragment (k-tile1) ----
            S8 xf;
            xf.i[0] = pk2(xa.x, xa.y); xf.i[1] = pk2(xa.z, xa.w);
            xf.i[2] = pk2(xb.x, xb.y); xf.i[3] = pk2(xb.z, xb.w);

            // ---- 14 MFMAs: all 112 gate preacts (scaled), bias as C-init ----
            float4v acc[7];
            #pragma unroll
            for (int mt = 0; mt < 7; ++mt)
                acc[mt] = __builtin_amdgcn_mfma_f32_16x16x32_bf16(wa0[mt], hfrag, biasv[mt], 0, 0, 0);
            #pragma unroll
            for (int mt = 0; mt < 7; ++mt)
                acc[mt] = __builtin_amdgcn_mfma_f32_16x16x32_bf16(wa1[mt], xf.s, acc[mt], 0, 0, 0);

            // prefetch x for next step (hidden under combine)
            if (tt + 1 < TC) {
                xa = *(const float4*)&xrow[rbase + (tt + 1) * IN_F + 0];
                xb = *(const float4*)&xrow[rbase + (tt + 1) * IN_F + 4];
            }

            // ---- in-register combine: unit q*7+mt, batch m ----
            #pragma unroll
            for (int mt = 0; mt < 7; ++mt) {
                float4v a = acc[mt];
                float e0 = __builtin_amdgcn_exp2f(a[0]);   // e^-i
                float e1 = __builtin_amdgcn_exp2f(a[1]);   // e^-f
                float e2 = __builtin_amdgcn_exp2f(a[2]);   // e^-2g
                float e3 = __builtin_amdgcn_exp2f(a[3]);   // e^-o
                float av = 1.0f + e0, bv = 1.0f + e1, dv = 1.0f + e2, vv = 1.0f + e3;
                float pd = av * dv;
                float rv = __builtin_amdgcn_rcpf(pd * bv);
                float sf = pd * rv;                         // sigma(f)
                float ig = (1.0f - e2) * bv * rv;           // sigma(i)*tanh(g)
                cc[mt] = fmaf(sf, cc[mt], ig);
                float ec = __builtin_amdgcn_exp2f(cc[mt] * (-2.0f * L1));
                float wv = 1.0f + ec;
                float r2 = __builtin_amdgcn_rcpf(vv * wv);
                hn[mt] = (1.0f - ec) * r2;                  // sigma(o)*tanh(c)
            }

            // ---- pack h -> next B-fragment (identity placement) ----
            S8 hf;
            hf.i[0] = pk2(hn[0], hn[1]); hf.i[1] = pk2(hn[2], hn[3]);
            hf.i[2] = pk2(hn[4], hn[5]); hf.i[3] = pk2(hn[6], 0.0f);
            hfrag = hf.s;
        }
    }

    // ---- epilogue: out[b][o] = sum_u h[u]*W_out[o][u] + b_out[o] ----
    float po[OUT_N];
    #pragma unroll
    for (int o = 0; o < OUT_N; ++o) {
        float sacc = 0.0f;
        #pragma unroll
        for (int mt = 0; mt < 7; ++mt)
            sacc = fmaf(hn[mt], W_out[o * HID + (q * 7 + mt)], sacc);
        sacc += __shfl_xor(sacc, 16, 64);
        sacc += __shfl_xor(sacc, 32, 64);
        po[o] = sacc;
    }
    if (l < WB) {
        out[(b0 + m) * OUT_N + 0] = po[0] + b_out[0];
        out[(b0 + m) * OUT_N + 1] = po[1] + b_out[1];
    }
}

extern "C" void kernel_launch(void* const* d_in, const int* in_sizes, int n_in,
                              void* d_out, int out_size, void* d_ws, size_t ws_size,
                              hipStream_t stream) {
    const float* x     = (const float*)d_in[0];
    const float* W_ih  = (const float*)d_in[1];
    const float* W_hh  = (const float*)d_in[2];
    const float* b_ih  = (const float*)d_in[3];
    const float* b_hh  = (const float*)d_in[4];
    const float* W_out = (const float*)d_in[5];
    const float* b_out = (const float*)d_in[6];
    float* out = (float*)d_out;

    lstm_reg<<<BATCH / WB, 64, 0, stream>>>(
        x, W_ih, W_hh, b_ih, b_hh, W_out, b_out, out);
}